// Round 2
// baseline (646.707 us; speedup 1.0000x reference)
//
#include <hip/hip_runtime.h>

// Problem constants
#define B_    2
#define S_    2048
#define DIN   1024
#define DOUT  1024
#define H_    16
#define HD_   64
#define M_    (B_ * S_)   // 4096 rows total

typedef __bf16 bf16x8 __attribute__((ext_vector_type(8)));
typedef float  f32x4  __attribute__((ext_vector_type(4)));

__device__ __forceinline__ f32x4 MFMA(bf16x8 a, bf16x8 b, f32x4 c) {
    return __builtin_amdgcn_mfma_f32_16x16x32_bf16(a, b, c, 0, 0, 0);
}

// float -> bf16 bits, round-to-nearest-even
__device__ __forceinline__ unsigned short f2b(float f) {
    union { float f; unsigned int u; } v; v.f = f;
    unsigned int u = v.u;
    return (unsigned short)((u + 0x7fffu + ((u >> 16) & 1u)) >> 16);
}

// async global->LDS, 16B per lane; LDS dest = wave-uniform base + lane*16
#define GLDS(gp, lp) __builtin_amdgcn_global_load_lds( \
    (const __attribute__((address_space(1))) void*)(gp), \
    (__attribute__((address_space(3))) void*)(lp), 16, 0, 0)

// ---------------- convert x (f32 -> bf16), vectorized ----------------
__global__ void k_cvt_x(const float* __restrict__ x, unsigned short* __restrict__ xb) {
    int i = (blockIdx.x * blockDim.x + threadIdx.x) * 4;
    float4 v = *reinterpret_cast<const float4*>(x + i);
    ushort4 o;
    o.x = f2b(v.x); o.y = f2b(v.y); o.z = f2b(v.z); o.w = f2b(v.w);
    *reinterpret_cast<ushort4*>(xb + i) = o;
}

// ------------- convert + transpose weight (f32 KxN -> bf16 NxK) -------------
__global__ void k_cvt_wT(const float* __restrict__ w, unsigned short* __restrict__ wt) {
    __shared__ float tile[32][33];
    int n0 = blockIdx.x * 32, k0 = blockIdx.y * 32;
    int tx = threadIdx.x, ty = threadIdx.y;
    for (int i = 0; i < 4; i++)
        tile[ty + i * 8][tx] = w[(size_t)(k0 + ty + i * 8) * DOUT + n0 + tx];
    __syncthreads();
    for (int i = 0; i < 4; i++)
        wt[(size_t)(n0 + ty + i * 8) * DIN + k0 + tx] = f2b(tile[tx][ty + i * 8]);
}

// ---------------- bf16 MFMA GEMM: C[M,N] = A[M,K] @ Bt[N,K]^T ----------------
// OUT_MODE 2: f32 out + bias
// OUT_MODE 3: fused QKV scatter (Q,K row-major bf16; V transposed per (b,h))
// 128x128 tile, 4 waves (2x2), BK=32, global_load_lds staging (m97 structure).
template <int OUT_MODE>
__global__ __launch_bounds__(256) void k_gemm(const unsigned short* __restrict__ A,
                                              const unsigned short* __restrict__ Bt,
                                              unsigned short* __restrict__ Cq,
                                              unsigned short* __restrict__ Ck,
                                              unsigned short* __restrict__ Cvt,
                                              float* __restrict__ Cf,
                                              const float* __restrict__ bias,
                                              int M, int N, int K) {
    __shared__ __align__(16) unsigned short As[128 * 32];
    __shared__ __align__(16) unsigned short Bs[128 * 32];
    int m0 = blockIdx.y * 128, n0 = blockIdx.x * 128;
    int tid = threadIdx.x;
    int wid = tid >> 6, lane = tid & 63;
    int wm = wid >> 1, wn = wid & 1;
    int lr = lane & 15, lg = lane >> 4;

    f32x4 acc[4][4] = {};

    int ar = wid * 16 + (lane >> 2);   // staging row within 64-row half
    int ac = (lane & 3) * 8;           // staging col (elements)

    for (int k0 = 0; k0 < K; k0 += 32) {
        GLDS(A  + (size_t)(m0 + ar) * K + k0 + ac,      (char*)As + wid * 1024);
        GLDS(A  + (size_t)(m0 + 64 + ar) * K + k0 + ac, (char*)As + 4096 + wid * 1024);
        GLDS(Bt + (size_t)(n0 + ar) * K + k0 + ac,      (char*)Bs + wid * 1024);
        GLDS(Bt + (size_t)(n0 + 64 + ar) * K + k0 + ac, (char*)Bs + 4096 + wid * 1024);
        __syncthreads();

        bf16x8 af[4], bf[4];
        for (int mi = 0; mi < 4; mi++)
            af[mi] = *reinterpret_cast<const bf16x8*>(&As[(wm * 64 + mi * 16 + lr) * 32 + lg * 8]);
        for (int ni = 0; ni < 4; ni++)
            bf[ni] = *reinterpret_cast<const bf16x8*>(&Bs[(wn * 64 + ni * 16 + lr) * 32 + lg * 8]);
        for (int mi = 0; mi < 4; mi++)
            for (int ni = 0; ni < 4; ni++)
                acc[mi][ni] = MFMA(af[mi], bf[ni], acc[mi][ni]);
        __syncthreads();
    }

    for (int mi = 0; mi < 4; mi++)
        for (int ni = 0; ni < 4; ni++)
            for (int i = 0; i < 4; i++) {
                int row = m0 + wm * 64 + mi * 16 + lg * 4 + i;
                int col = n0 + wn * 64 + ni * 16 + lr;
                float v = acc[mi][ni][i];
                if (OUT_MODE == 2) {
                    Cf[(size_t)row * N + col] = v + bias[col];
                } else {
                    if (col < 1024) {
                        Cq[(size_t)row * 1024 + col] = f2b(v);
                    } else if (col < 2048) {
                        Ck[(size_t)row * 1024 + col - 1024] = f2b(v);
                    } else {
                        int c = col - 2048;
                        int hh = c >> 6, hd = c & (HD_ - 1);
                        int bb = row >> 11, ss = row & (S_ - 1);
                        Cvt[((size_t)(bb * H_ + hh) * HD_ + hd) * S_ + ss] = f2b(v);
                    }
                }
            }
}

// ---------------- flash attention (causal), bf16 in/out ----------------
// grid (S/64, B*H), 256 threads (4 waves x 16 q-rows). KV tiles of 64, staged
// in LDS via global_load_lds (pre-swizzled source), double-buffered, counted
// vmcnt so next tile's loads stay in flight across the compute.
__global__ __launch_bounds__(256) void k_attn(const unsigned short* __restrict__ Q,
                                              const unsigned short* __restrict__ Kg,
                                              const unsigned short* __restrict__ Vt,
                                              unsigned short* __restrict__ ctx) {
    int qt = gridDim.x - 1 - blockIdx.x;   // heavy causal blocks dispatch first
    int bh = blockIdx.y;
    int b = bh >> 4, h = bh & 15;
    int tid = threadIdx.x, wid = tid >> 6, lane = tid & 63;
    int lr = lane & 15, lg = lane >> 4;
    int q0 = qt * 64 + wid * 16;

    __shared__ __align__(16) unsigned short Ks[2][64 * 64];   // [kv][hd], swizzled
    __shared__ __align__(16) unsigned short Vs[2][64 * 64];   // [hd][s],  swizzled
    __shared__ __align__(16) unsigned short p_lds[4][16 * 64];
    unsigned short* pl = p_lds[wid];

    const unsigned short* Qp = Q  + (size_t)b * S_ * DOUT + (size_t)h * HD_;
    const unsigned short* Kp = Kg + (size_t)b * S_ * DOUT + (size_t)h * HD_;
    const unsigned short* Vp = Vt + (size_t)(b * H_ + h) * HD_ * S_;

    // Q fragments (registers), force-resolve before the pipelined loop so the
    // compiler's waitcnt for them doesn't land inside the loop.
    bf16x8 qf0 = *reinterpret_cast<const bf16x8*>(&Qp[(size_t)(q0 + lr) * DOUT + lg * 8]);
    bf16x8 qf1 = *reinterpret_cast<const bf16x8*>(&Qp[(size_t)(q0 + lr) * DOUT + 32 + lg * 8]);
    asm volatile("" : "+v"(qf0), "+v"(qf1));

    // staging: lane covers LDS bytes [chunk*1024 + lane*16); pre-swizzle the
    // global source so a swizzled ds_read returns linear data.
    int srow_base = (lane >> 3);                         // 0..7 within chunk
    int scolB = ((lane & 7) ^ (lane >> 3)) << 4;         // swizzled col bytes
    int sel = scolB >> 1;                                // col elements

#define STAGE_KV(buf, t)                                                           \
    {                                                                              \
        int kv0_ = (t) * 64;                                                       \
        for (int c = 0; c < 2; c++) {                                              \
            int chunk = wid * 2 + c;                                               \
            int row = chunk * 8 + srow_base;                                       \
            GLDS(Kp + (size_t)(kv0_ + row) * DOUT + sel,                           \
                 (char*)&Ks[buf][0] + chunk * 1024);                               \
            GLDS(Vp + (size_t)row * S_ + kv0_ + sel,                               \
                 (char*)&Vs[buf][0] + chunk * 1024);                               \
        }                                                                          \
    }

    STAGE_KV(0, 0)

    f32x4 o[4] = {};
    float m_run[4], l_run[4];
    for (int i = 0; i < 4; i++) { m_run[i] = -1e30f; l_run[i] = 0.f; }

    int ntile = qt + 1;   // same for all 4 waves of the block
    for (int t = 0; t < ntile; t++) {
        int cur = t & 1;
        if (t + 1 < ntile) {
            STAGE_KV(cur ^ 1, t + 1)
            asm volatile("s_waitcnt vmcnt(4)" ::: "memory");  // cur landed, next in flight
        } else {
            asm volatile("s_waitcnt vmcnt(0)" ::: "memory");
        }
        __builtin_amdgcn_s_barrier();

        int kv0 = t * 64;
        const unsigned short* Kt = Ks[cur];
        const unsigned short* Vl = Vs[cur];
        int rxor = (lr & 7) << 4;   // row-XOR for swizzled reads (row%8 == lr%8)

        // scores = Q @ K^T  (C: row q = lg*4+i, col kv = nf*16+lr)
        f32x4 sco[4];
        for (int nf = 0; nf < 4; nf++) {
            f32x4 z = {};
            for (int kk = 0; kk < 2; kk++) {
                bf16x8 kf = *reinterpret_cast<const bf16x8*>(
                    &Kt[(nf * 16 + lr) * 64 + (((kk * 64 + lg * 16) ^ rxor) >> 1)]);
                z = MFMA(kk ? qf1 : qf0, kf, z);
            }
            sco[nf] = z;
        }
        // online softmax per q-row
        for (int i = 0; i < 4; i++) {
            int q = q0 + lg * 4 + i;
            int prow = lg * 4 + i;
            int pxor = (prow & 7) << 4;
            float rm = -1e30f;
            for (int nf = 0; nf < 4; nf++) {
                float s = sco[nf][i] * 0.125f;      // 1/sqrt(64)
                if (kv0 + nf * 16 + lr > q) s = -1e30f;
                sco[nf][i] = s;
                rm = fmaxf(rm, s);
            }
            rm = fmaxf(rm, __shfl_xor(rm, 1, 64));
            rm = fmaxf(rm, __shfl_xor(rm, 2, 64));
            rm = fmaxf(rm, __shfl_xor(rm, 4, 64));
            rm = fmaxf(rm, __shfl_xor(rm, 8, 64));
            float mnew = fmaxf(m_run[i], rm);
            float sum = 0.f;
            for (int nf = 0; nf < 4; nf++) {
                float p = __expf(sco[nf][i] - mnew);
                sum += p;
                pl[prow * 64 + ((((nf * 16 + lr) << 1) ^ pxor) >> 1)] = f2b(p);
            }
            sum += __shfl_xor(sum, 1, 64);
            sum += __shfl_xor(sum, 2, 64);
            sum += __shfl_xor(sum, 4, 64);
            sum += __shfl_xor(sum, 8, 64);
            float cf = __expf(m_run[i] - mnew);
            l_run[i] = l_run[i] * cf + sum;
            m_run[i] = mnew;
            for (int nd = 0; nd < 4; nd++) o[nd][i] *= cf;
        }
        // P @ V (P via per-wave LDS re-layout; V from staged tile)
        bf16x8 pf[2];
        for (int kk = 0; kk < 2; kk++)
            pf[kk] = *reinterpret_cast<const bf16x8*>(
                &pl[lr * 64 + (((kk * 64 + lg * 16) ^ rxor) >> 1)]);
        for (int nd = 0; nd < 4; nd++)
            for (int kk = 0; kk < 2; kk++) {
                bf16x8 vf = *reinterpret_cast<const bf16x8*>(
                    &Vl[(nd * 16 + lr) * 64 + (((kk * 64 + lg * 16) ^ rxor) >> 1)]);
                o[nd] = MFMA(pf[kk], vf, o[nd]);
            }
        __builtin_amdgcn_s_barrier();   // all waves done with buf before restage
    }

    for (int nd = 0; nd < 4; nd++)
        for (int i = 0; i < 4; i++) {
            float v = o[nd][i] / l_run[i];
            ctx[((size_t)b * S_ + q0 + lg * 4 + i) * DOUT + h * HD_ + nd * 16 + lr] = f2b(v);
        }
#undef STAGE_KV
}

extern "C" void kernel_launch(void* const* d_in, const int* in_sizes, int n_in,
                              void* d_out, int out_size, void* d_ws, size_t ws_size,
                              hipStream_t stream) {
    const float* x  = (const float*)d_in[0];
    const float* Wq = (const float*)d_in[1];
    const float* Wk = (const float*)d_in[2];
    const float* Wv = (const float*)d_in[3];
    const float* Wo = (const float*)d_in[4];
    const float* bo = (const float*)d_in[5];
    float* out = (float*)d_out;
    char* ws = (char*)d_ws;
    const size_t MB = 1u << 20;

    unsigned short* xb    = (unsigned short*)(ws);            // 8 MB
    unsigned short* WqkvT = (unsigned short*)(ws + 8 * MB);   // 6 MB ([3072][1024])
    unsigned short* WoT   = (unsigned short*)(ws + 14 * MB);  // 2 MB
    unsigned short* Qb    = (unsigned short*)(ws + 16 * MB);  // 8 MB
    unsigned short* Kb    = (unsigned short*)(ws + 24 * MB);  // 8 MB
    unsigned short* Vtb   = (unsigned short*)(ws + 32 * MB);  // 8 MB
    unsigned short* ctx   = xb;                               // reuse

    (void)in_sizes; (void)n_in; (void)out_size; (void)ws_size;

    k_cvt_x<<<dim3((M_ * DIN) / 1024), 256, 0, stream>>>(x, xb);

    dim3 tb(32, 8), tg(DOUT / 32, DIN / 32);
    k_cvt_wT<<<tg, tb, 0, stream>>>(Wq, WqkvT);
    k_cvt_wT<<<tg, tb, 0, stream>>>(Wk, WqkvT + (size_t)1024 * DIN);
    k_cvt_wT<<<tg, tb, 0, stream>>>(Wv, WqkvT + (size_t)2048 * DIN);
    k_cvt_wT<<<tg, tb, 0, stream>>>(Wo, WoT);

    // fused QKV projection: C[4096,3072] = xb @ WqkvT^T, scattered to Q/K/Vt
    dim3 gq(3072 / 128, M_ / 128);
    k_gemm<3><<<gq, 256, 0, stream>>>(xb, WqkvT, Qb, Kb, Vtb, nullptr, nullptr,
                                      M_, 3072, DIN);

    dim3 ga(S_ / 64, B_ * H_);
    k_attn<<<ga, 256, 0, stream>>>(Qb, Kb, Vtb, ctx);

    dim3 go(DOUT / 128, M_ / 128);
    k_gemm<2><<<go, 256, 0, stream>>>(ctx, WoT, nullptr, nullptr, nullptr,
                                      out, bo, M_, DOUT, DOUT);
}

// Round 3
// 198.690 us; speedup vs baseline: 3.2549x; 3.2549x over previous
//
#include <hip/hip_runtime.h>

// Problem constants
#define B_    2
#define S_    2048
#define DIN   1024
#define DOUT  1024
#define H_    16
#define HD_   64
#define M_    (B_ * S_)   // 4096 rows total

typedef __bf16 bf16x8 __attribute__((ext_vector_type(8)));
typedef float  f32x4  __attribute__((ext_vector_type(4)));

__device__ __forceinline__ f32x4 MFMA(bf16x8 a, bf16x8 b, f32x4 c) {
    return __builtin_amdgcn_mfma_f32_16x16x32_bf16(a, b, c, 0, 0, 0);
}

// float -> bf16 bits, round-to-nearest-even
__device__ __forceinline__ unsigned short f2b(float f) {
    union { float f; unsigned int u; } v; v.f = f;
    unsigned int u = v.u;
    return (unsigned short)((u + 0x7fffu + ((u >> 16) & 1u)) >> 16);
}

// async global->LDS, 16B per lane; LDS dest = wave-uniform base + lane*16
#define GLDS(gp, lp) __builtin_amdgcn_global_load_lds( \
    (const __attribute__((address_space(1))) void*)(gp), \
    (__attribute__((address_space(3))) void*)(lp), 16, 0, 0)

// ---------------- convert x (f32 -> bf16), vectorized ----------------
__global__ void k_cvt_x(const float* __restrict__ x, unsigned short* __restrict__ xb) {
    int i = (blockIdx.x * blockDim.x + threadIdx.x) * 4;
    float4 v = *reinterpret_cast<const float4*>(x + i);
    ushort4 o;
    o.x = f2b(v.x); o.y = f2b(v.y); o.z = f2b(v.z); o.w = f2b(v.w);
    *reinterpret_cast<ushort4*>(xb + i) = o;
}

// ------------- convert + transpose weight (f32 KxN -> bf16 NxK) -------------
__global__ void k_cvt_wT(const float* __restrict__ w, unsigned short* __restrict__ wt) {
    __shared__ float tile[32][33];
    int n0 = blockIdx.x * 32, k0 = blockIdx.y * 32;
    int tx = threadIdx.x, ty = threadIdx.y;
    for (int i = 0; i < 4; i++)
        tile[ty + i * 8][tx] = w[(size_t)(k0 + ty + i * 8) * DOUT + n0 + tx];
    __syncthreads();
    for (int i = 0; i < 4; i++)
        wt[(size_t)(n0 + ty + i * 8) * DIN + k0 + tx] = f2b(tile[tx][ty + i * 8]);
}

// ---- transpose V per (b,h): [b*S+s][h*HD+hd] -> [(b*H+h)*HD+hd][s] ----
// 64x64 tile per block; 16B vector loads and stores on both sides.
__global__ __launch_bounds__(256) void k_trV(const unsigned short* __restrict__ V,
                                             unsigned short* __restrict__ Vt) {
    __shared__ unsigned short tile[64][72];   // 144B row stride (16B aligned)
    int st = blockIdx.x, bh = blockIdx.y;
    int b = bh >> 4, h = bh & 15;
    int t = threadIdx.x;
    int r = t >> 2, c = (t & 3) << 4;
    const unsigned short* src = V + (size_t)(b * S_ + st * 64 + r) * DOUT + h * HD_ + c;
    *reinterpret_cast<int4*>(&tile[r][c])     = *reinterpret_cast<const int4*>(src);
    *reinterpret_cast<int4*>(&tile[r][c + 8]) = *reinterpret_cast<const int4*>(src + 8);
    __syncthreads();
    unsigned short o[16];
    for (int j = 0; j < 16; j++) o[j] = tile[c + j][r];   // r is hd on this side
    unsigned short* dst = Vt + (size_t)(bh * 64 + r) * S_ + st * 64 + c;
    *reinterpret_cast<int4*>(dst)     = *reinterpret_cast<int4*>(&o[0]);
    *reinterpret_cast<int4*>(dst + 8) = *reinterpret_cast<int4*>(&o[8]);
}

// ---------------- bf16 MFMA GEMM: C[M,N] = A[M,K] @ Bt[N,K]^T ----------------
// OUT_MODE 0: QKV fused — row-major bf16 into Cq/Ck/Cv by col range (block-uniform)
// OUT_MODE 2: f32 out + bias
// 128x128 tile, 4 waves (2x2), BK=32, global_load_lds staging, XCD swizzle.
template <int OUT_MODE>
__global__ __launch_bounds__(256) void k_gemm(const unsigned short* __restrict__ A,
                                              const unsigned short* __restrict__ Bt,
                                              unsigned short* __restrict__ Cq,
                                              unsigned short* __restrict__ Ck,
                                              unsigned short* __restrict__ Cv,
                                              float* __restrict__ Cf,
                                              const float* __restrict__ bias,
                                              int M, int N, int K, int nbx) {
    __shared__ __align__(16) unsigned short As[128 * 32];
    __shared__ __align__(16) unsigned short Bs[128 * 32];

    // XCD-aware swizzle: contiguous chunk of block-rows per XCD (nwg % 8 == 0)
    int nwg = gridDim.x;
    int chunk = nwg >> 3;
    int bid = blockIdx.x;
    int nid = (bid & 7) * chunk + (bid >> 3);
    int by = nid / nbx, bx = nid - by * nbx;
    int m0 = by * 128, n0 = bx * 128;

    int tid = threadIdx.x;
    int wid = tid >> 6, lane = tid & 63;
    int wm = wid >> 1, wn = wid & 1;
    int lr = lane & 15, lg = lane >> 4;

    f32x4 acc[4][4] = {};

    int ar = wid * 16 + (lane >> 2);   // staging row within 64-row half
    int ac = (lane & 3) * 8;           // staging col (elements)

    for (int k0 = 0; k0 < K; k0 += 32) {
        GLDS(A  + (size_t)(m0 + ar) * K + k0 + ac,      (char*)As + wid * 1024);
        GLDS(A  + (size_t)(m0 + 64 + ar) * K + k0 + ac, (char*)As + 4096 + wid * 1024);
        GLDS(Bt + (size_t)(n0 + ar) * K + k0 + ac,      (char*)Bs + wid * 1024);
        GLDS(Bt + (size_t)(n0 + 64 + ar) * K + k0 + ac, (char*)Bs + 4096 + wid * 1024);
        __syncthreads();

        bf16x8 af[4], bf[4];
        for (int mi = 0; mi < 4; mi++)
            af[mi] = *reinterpret_cast<const bf16x8*>(&As[(wm * 64 + mi * 16 + lr) * 32 + lg * 8]);
        for (int ni = 0; ni < 4; ni++)
            bf[ni] = *reinterpret_cast<const bf16x8*>(&Bs[(wn * 64 + ni * 16 + lr) * 32 + lg * 8]);
        for (int mi = 0; mi < 4; mi++)
            for (int ni = 0; ni < 4; ni++)
                acc[mi][ni] = MFMA(af[mi], bf[ni], acc[mi][ni]);
        __syncthreads();
    }

    for (int mi = 0; mi < 4; mi++)
        for (int ni = 0; ni < 4; ni++)
            for (int i = 0; i < 4; i++) {
                int row = m0 + wm * 64 + mi * 16 + lg * 4 + i;
                int col = n0 + wn * 64 + ni * 16 + lr;
                float v = acc[mi][ni][i];
                if (OUT_MODE == 2) {
                    Cf[(size_t)row * N + col] = v + bias[col];
                } else {
                    unsigned short vb = f2b(v);
                    if (col < 1024)       Cq[(size_t)row * 1024 + col] = vb;
                    else if (col < 2048)  Ck[(size_t)row * 1024 + (col - 1024)] = vb;
                    else                  Cv[(size_t)row * 1024 + (col - 2048)] = vb;
                }
            }
}

// ---------------- flash attention (causal), bf16 in/out ----------------
// grid (S/64, B*H), 256 threads (4 waves x 16 q-rows). KV tiles of 64, staged
// in LDS via global_load_lds (pre-swizzled source), double-buffered, counted
// vmcnt so next tile's loads stay in flight across the compute.
__global__ __launch_bounds__(256) void k_attn(const unsigned short* __restrict__ Q,
                                              const unsigned short* __restrict__ Kg,
                                              const unsigned short* __restrict__ Vt,
                                              unsigned short* __restrict__ ctx) {
    int qt = gridDim.x - 1 - blockIdx.x;   // heavy causal blocks dispatch first
    int bh = blockIdx.y;
    int b = bh >> 4, h = bh & 15;
    int tid = threadIdx.x, wid = tid >> 6, lane = tid & 63;
    int lr = lane & 15, lg = lane >> 4;
    int q0 = qt * 64 + wid * 16;

    __shared__ __align__(16) unsigned short Ks[2][64 * 64];   // [kv][hd], swizzled
    __shared__ __align__(16) unsigned short Vs[2][64 * 64];   // [hd][s],  swizzled
    __shared__ __align__(16) unsigned short p_lds[4][16 * 64];
    unsigned short* pl = p_lds[wid];

    const unsigned short* Qp = Q  + (size_t)b * S_ * DOUT + (size_t)h * HD_;
    const unsigned short* Kp = Kg + (size_t)b * S_ * DOUT + (size_t)h * HD_;
    const unsigned short* Vp = Vt + (size_t)(b * H_ + h) * HD_ * S_;

    bf16x8 qf0 = *reinterpret_cast<const bf16x8*>(&Qp[(size_t)(q0 + lr) * DOUT + lg * 8]);
    bf16x8 qf1 = *reinterpret_cast<const bf16x8*>(&Qp[(size_t)(q0 + lr) * DOUT + 32 + lg * 8]);
    asm volatile("" : "+v"(qf0), "+v"(qf1));

    int srow_base = (lane >> 3);                         // 0..7 within chunk
    int scolB = ((lane & 7) ^ (lane >> 3)) << 4;         // swizzled col bytes
    int sel = scolB >> 1;                                // col elements

#define STAGE_KV(buf, t)                                                           \
    {                                                                              \
        int kv0_ = (t) * 64;                                                       \
        for (int c = 0; c < 2; c++) {                                              \
            int chunk = wid * 2 + c;                                               \
            int row = chunk * 8 + srow_base;                                       \
            GLDS(Kp + (size_t)(kv0_ + row) * DOUT + sel,                           \
                 (char*)&Ks[buf][0] + chunk * 1024);                               \
            GLDS(Vp + (size_t)row * S_ + kv0_ + sel,                               \
                 (char*)&Vs[buf][0] + chunk * 1024);                               \
        }                                                                          \
    }

    STAGE_KV(0, 0)

    f32x4 o[4] = {};
    float m_run[4], l_run[4];
    for (int i = 0; i < 4; i++) { m_run[i] = -1e30f; l_run[i] = 0.f; }

    int ntile = qt + 1;   // same for all 4 waves of the block
    for (int t = 0; t < ntile; t++) {
        int cur = t & 1;
        if (t + 1 < ntile) {
            STAGE_KV(cur ^ 1, t + 1)
            asm volatile("s_waitcnt vmcnt(4)" ::: "memory");  // cur landed, next in flight
        } else {
            asm volatile("s_waitcnt vmcnt(0)" ::: "memory");
        }
        __builtin_amdgcn_s_barrier();

        int kv0 = t * 64;
        const unsigned short* Kt = Ks[cur];
        const unsigned short* Vl = Vs[cur];
        int rxor = (lr & 7) << 4;   // row-XOR for swizzled reads (row%8 == lr%8)

        // scores = Q @ K^T  (C: row q = lg*4+i, col kv = nf*16+lr)
        f32x4 sco[4];
        __builtin_amdgcn_s_setprio(1);
        for (int nf = 0; nf < 4; nf++) {
            f32x4 z = {};
            for (int kk = 0; kk < 2; kk++) {
                bf16x8 kf = *reinterpret_cast<const bf16x8*>(
                    &Kt[(nf * 16 + lr) * 64 + (((kk * 64 + lg * 16) ^ rxor) >> 1)]);
                z = MFMA(kk ? qf1 : qf0, kf, z);
            }
            sco[nf] = z;
        }
        __builtin_amdgcn_s_setprio(0);
        // online softmax per q-row
        for (int i = 0; i < 4; i++) {
            int q = q0 + lg * 4 + i;
            int prow = lg * 4 + i;
            int pxor = (prow & 7) << 4;
            float rm = -1e30f;
            for (int nf = 0; nf < 4; nf++) {
                float s = sco[nf][i] * 0.125f;      // 1/sqrt(64)
                if (kv0 + nf * 16 + lr > q) s = -1e30f;
                sco[nf][i] = s;
                rm = fmaxf(rm, s);
            }
            rm = fmaxf(rm, __shfl_xor(rm, 1, 64));
            rm = fmaxf(rm, __shfl_xor(rm, 2, 64));
            rm = fmaxf(rm, __shfl_xor(rm, 4, 64));
            rm = fmaxf(rm, __shfl_xor(rm, 8, 64));
            float mnew = fmaxf(m_run[i], rm);
            float sum = 0.f;
            for (int nf = 0; nf < 4; nf++) {
                float p = __expf(sco[nf][i] - mnew);
                sum += p;
                pl[prow * 64 + ((((nf * 16 + lr) << 1) ^ pxor) >> 1)] = f2b(p);
            }
            sum += __shfl_xor(sum, 1, 64);
            sum += __shfl_xor(sum, 2, 64);
            sum += __shfl_xor(sum, 4, 64);
            sum += __shfl_xor(sum, 8, 64);
            float cf = __expf(m_run[i] - mnew);
            l_run[i] = l_run[i] * cf + sum;
            m_run[i] = mnew;
            for (int nd = 0; nd < 4; nd++) o[nd][i] *= cf;
        }
        // P @ V (P via per-wave LDS re-layout; V from staged tile)
        bf16x8 pf[2];
        for (int kk = 0; kk < 2; kk++)
            pf[kk] = *reinterpret_cast<const bf16x8*>(
                &pl[lr * 64 + (((kk * 64 + lg * 16) ^ rxor) >> 1)]);
        __builtin_amdgcn_s_setprio(1);
        for (int nd = 0; nd < 4; nd++)
            for (int kk = 0; kk < 2; kk++) {
                bf16x8 vf = *reinterpret_cast<const bf16x8*>(
                    &Vl[(nd * 16 + lr) * 64 + (((kk * 64 + lg * 16) ^ rxor) >> 1)]);
                o[nd] = MFMA(pf[kk], vf, o[nd]);
            }
        __builtin_amdgcn_s_setprio(0);
        __builtin_amdgcn_s_barrier();   // all waves done with buf before restage
    }

    for (int nd = 0; nd < 4; nd++)
        for (int i = 0; i < 4; i++) {
            float v = o[nd][i] / l_run[i];
            ctx[((size_t)b * S_ + q0 + lg * 4 + i) * DOUT + h * HD_ + nd * 16 + lr] = f2b(v);
        }
#undef STAGE_KV
}

extern "C" void kernel_launch(void* const* d_in, const int* in_sizes, int n_in,
                              void* d_out, int out_size, void* d_ws, size_t ws_size,
                              hipStream_t stream) {
    const float* x  = (const float*)d_in[0];
    const float* Wq = (const float*)d_in[1];
    const float* Wk = (const float*)d_in[2];
    const float* Wv = (const float*)d_in[3];
    const float* Wo = (const float*)d_in[4];
    const float* bo = (const float*)d_in[5];
    float* out = (float*)d_out;
    char* ws = (char*)d_ws;
    const size_t MB = 1u << 20;

    // workspace layout (40 MB, with lifetime-based reuse):
    //  0..8   xb (x bf16)        -> later Vt (xb dead after QKV GEMM)
    //  8..14  WqkvT              (dead after QKV GEMM)
    // 14..16  WoT                (needed at end)
    // 16..24  Qb
    // 24..32  Kb
    // 32..40  Vb (row-major)     -> later ctx (Vb dead after k_trV)
    unsigned short* xb    = (unsigned short*)(ws);
    unsigned short* Vtb   = (unsigned short*)(ws);            // reuse of xb
    unsigned short* WqkvT = (unsigned short*)(ws + 8 * MB);
    unsigned short* WoT   = (unsigned short*)(ws + 14 * MB);
    unsigned short* Qb    = (unsigned short*)(ws + 16 * MB);
    unsigned short* Kb    = (unsigned short*)(ws + 24 * MB);
    unsigned short* Vb    = (unsigned short*)(ws + 32 * MB);
    unsigned short* ctx   = Vb;                               // reuse of Vb

    (void)in_sizes; (void)n_in; (void)out_size; (void)ws_size;

    k_cvt_x<<<dim3((M_ * DIN) / 1024), 256, 0, stream>>>(x, xb);

    dim3 tb(32, 8), tg(DOUT / 32, DIN / 32);
    k_cvt_wT<<<tg, tb, 0, stream>>>(Wq, WqkvT);
    k_cvt_wT<<<tg, tb, 0, stream>>>(Wk, WqkvT + (size_t)1024 * DIN);
    k_cvt_wT<<<tg, tb, 0, stream>>>(Wv, WqkvT + (size_t)2048 * DIN);
    k_cvt_wT<<<tg, tb, 0, stream>>>(Wo, WoT);

    // fused QKV projection: C[4096,3072] = xb @ WqkvT^T -> Qb,Kb,Vb (row-major)
    k_gemm<0><<<768, 256, 0, stream>>>(xb, WqkvT, Qb, Kb, Vb, nullptr, nullptr,
                                       M_, 3072, DIN, 24);

    // V -> per-(b,h) transposed [hd][s]
    dim3 gt(S_ / 64, B_ * H_);
    k_trV<<<gt, 256, 0, stream>>>(Vb, Vtb);

    // causal flash attention (ctx overwrites Vb; reads Vtb which lives at ws+0)
    dim3 ga(S_ / 64, B_ * H_);
    k_attn<<<ga, 256, 0, stream>>>(Qb, Kb, Vtb, ctx);

    // output projection + bias (f32 out)
    k_gemm<2><<<256, 256, 0, stream>>>(ctx, WoT, nullptr, nullptr, nullptr,
                                       out, bo, M_, DOUT, DOUT, 8);
}

// Round 4
// 167.147 us; speedup vs baseline: 3.8691x; 1.1887x over previous
//
#include <hip/hip_runtime.h>

// Problem constants
#define B_    2
#define S_    2048
#define DIN   1024
#define DOUT  1024
#define H_    16
#define HD_   64
#define M_    (B_ * S_)   // 4096 rows total

typedef __bf16 bf16x8 __attribute__((ext_vector_type(8)));
typedef float  f32x4  __attribute__((ext_vector_type(4)));

__device__ __forceinline__ f32x4 MFMA(bf16x8 a, bf16x8 b, f32x4 c) {
    return __builtin_amdgcn_mfma_f32_16x16x32_bf16(a, b, c, 0, 0, 0);
}

// float -> bf16 bits, round-to-nearest-even
__device__ __forceinline__ unsigned short f2b(float f) {
    union { float f; unsigned int u; } v; v.f = f;
    unsigned int u = v.u;
    return (unsigned short)((u + 0x7fffu + ((u >> 16) & 1u)) >> 16);
}

// async global->LDS, 16B per lane; LDS dest = wave-uniform base + lane*16
#define GLDS(gp, lp) __builtin_amdgcn_global_load_lds( \
    (const __attribute__((address_space(1))) void*)(gp), \
    (__attribute__((address_space(3))) void*)(lp), 16, 0, 0)

// ---------------- convert x (f32 -> bf16), vectorized ----------------
__global__ void k_cvt_x(const float* __restrict__ x, unsigned short* __restrict__ xb) {
    int i = (blockIdx.x * blockDim.x + threadIdx.x) * 4;
    float4 v = *reinterpret_cast<const float4*>(x + i);
    ushort4 o;
    o.x = f2b(v.x); o.y = f2b(v.y); o.z = f2b(v.z); o.w = f2b(v.w);
    *reinterpret_cast<ushort4*>(xb + i) = o;
}

// ------------- convert + transpose weight (f32 KxN -> bf16 NxK) -------------
__global__ void k_cvt_wT(const float* __restrict__ w, unsigned short* __restrict__ wt) {
    __shared__ float tile[32][33];
    int n0 = blockIdx.x * 32, k0 = blockIdx.y * 32;
    int tx = threadIdx.x, ty = threadIdx.y;
    for (int i = 0; i < 4; i++)
        tile[ty + i * 8][tx] = w[(size_t)(k0 + ty + i * 8) * DOUT + n0 + tx];
    __syncthreads();
    for (int i = 0; i < 4; i++)
        wt[(size_t)(n0 + ty + i * 8) * DIN + k0 + tx] = f2b(tile[tx][ty + i * 8]);
}

// ---- transpose V per (b,h): [b*S+s][h*HD+hd] -> [(b*H+h)*HD+hd][s] ----
__global__ __launch_bounds__(256) void k_trV(const unsigned short* __restrict__ V,
                                             unsigned short* __restrict__ Vt) {
    __shared__ unsigned short tile[64][72];
    int st = blockIdx.x, bh = blockIdx.y;
    int b = bh >> 4, h = bh & 15;
    int t = threadIdx.x;
    int r = t >> 2, c = (t & 3) << 4;
    const unsigned short* src = V + (size_t)(b * S_ + st * 64 + r) * DOUT + h * HD_ + c;
    *reinterpret_cast<int4*>(&tile[r][c])     = *reinterpret_cast<const int4*>(src);
    *reinterpret_cast<int4*>(&tile[r][c + 8]) = *reinterpret_cast<const int4*>(src + 8);
    __syncthreads();
    unsigned short o[16];
    for (int j = 0; j < 16; j++) o[j] = tile[c + j][r];
    unsigned short* dst = Vt + (size_t)(bh * 64 + r) * S_ + st * 64 + c;
    *reinterpret_cast<int4*>(dst)     = *reinterpret_cast<int4*>(&o[0]);
    *reinterpret_cast<int4*>(dst + 8) = *reinterpret_cast<int4*>(&o[8]);
}

// ---------------- bf16 MFMA GEMM: C[M,N] = A[M,K] @ Bt[N,K]^T ----------------
// OUT_MODE 0: QKV fused — row-major bf16 into Cq/Ck/Cv by col range.
//             Q written PRE-SCALED by 1/sqrt(HD) = 0.125 (exact pow2).
// OUT_MODE 2: f32 out + bias
template <int OUT_MODE>
__global__ __launch_bounds__(256) void k_gemm(const unsigned short* __restrict__ A,
                                              const unsigned short* __restrict__ Bt,
                                              unsigned short* __restrict__ Cq,
                                              unsigned short* __restrict__ Ck,
                                              unsigned short* __restrict__ Cv,
                                              float* __restrict__ Cf,
                                              const float* __restrict__ bias,
                                              int M, int N, int K, int nbx) {
    __shared__ __align__(16) unsigned short As[128 * 32];
    __shared__ __align__(16) unsigned short Bs[128 * 32];

    // XCD-aware swizzle (nwg % 8 == 0)
    int nwg = gridDim.x;
    int chunk = nwg >> 3;
    int bid = blockIdx.x;
    int nid = (bid & 7) * chunk + (bid >> 3);
    int by = nid / nbx, bx = nid - by * nbx;
    int m0 = by * 128, n0 = bx * 128;

    int tid = threadIdx.x;
    int wid = tid >> 6, lane = tid & 63;
    int wm = wid >> 1, wn = wid & 1;
    int lr = lane & 15, lg = lane >> 4;

    f32x4 acc[4][4] = {};

    int ar = wid * 16 + (lane >> 2);
    int ac = (lane & 3) * 8;

    for (int k0 = 0; k0 < K; k0 += 32) {
        GLDS(A  + (size_t)(m0 + ar) * K + k0 + ac,      (char*)As + wid * 1024);
        GLDS(A  + (size_t)(m0 + 64 + ar) * K + k0 + ac, (char*)As + 4096 + wid * 1024);
        GLDS(Bt + (size_t)(n0 + ar) * K + k0 + ac,      (char*)Bs + wid * 1024);
        GLDS(Bt + (size_t)(n0 + 64 + ar) * K + k0 + ac, (char*)Bs + 4096 + wid * 1024);
        __syncthreads();

        bf16x8 af[4], bf[4];
        for (int mi = 0; mi < 4; mi++)
            af[mi] = *reinterpret_cast<const bf16x8*>(&As[(wm * 64 + mi * 16 + lr) * 32 + lg * 8]);
        for (int ni = 0; ni < 4; ni++)
            bf[ni] = *reinterpret_cast<const bf16x8*>(&Bs[(wn * 64 + ni * 16 + lr) * 32 + lg * 8]);
        for (int mi = 0; mi < 4; mi++)
            for (int ni = 0; ni < 4; ni++)
                acc[mi][ni] = MFMA(af[mi], bf[ni], acc[mi][ni]);
        __syncthreads();
    }

    for (int mi = 0; mi < 4; mi++)
        for (int ni = 0; ni < 4; ni++)
            for (int i = 0; i < 4; i++) {
                int row = m0 + wm * 64 + mi * 16 + lg * 4 + i;
                int col = n0 + wn * 64 + ni * 16 + lr;
                float v = acc[mi][ni][i];
                if (OUT_MODE == 2) {
                    Cf[(size_t)row * N + col] = v + bias[col];
                } else {
                    if (col < 1024)       Cq[(size_t)row * 1024 + col] = f2b(v * 0.125f);
                    else if (col < 2048)  Ck[(size_t)row * 1024 + (col - 1024)] = f2b(v);
                    else                  Cv[(size_t)row * 1024 + (col - 2048)] = f2b(v);
                }
            }
}

// ---- per-tile QK^T -> online softmax -> PV for one 16-row q-chunk ----
// Q pre-scaled by 1/sqrt(HD). Only diagonal tiles need the causal mask.
__device__ __forceinline__ void qk_sm_pv(const unsigned short* __restrict__ Kt,
                                         const unsigned short* __restrict__ Vl,
                                         unsigned short* __restrict__ pl,
                                         bf16x8 qf0, bf16x8 qf1,
                                         f32x4 (&o)[4], float (&m_run)[4],
                                         float (&l_run)[4],
                                         int q0, int kv0, bool diag,
                                         int lr, int lg, int rxor) {
    f32x4 sco[4];
    __builtin_amdgcn_s_setprio(1);
    for (int nf = 0; nf < 4; nf++) {
        f32x4 z = {};
        for (int kk = 0; kk < 2; kk++) {
            bf16x8 kf = *reinterpret_cast<const bf16x8*>(
                &Kt[(nf * 16 + lr) * 64 + (((kk * 64 + lg * 16) ^ rxor) >> 1)]);
            z = MFMA(kk ? qf1 : qf0, kf, z);
        }
        sco[nf] = z;
    }
    __builtin_amdgcn_s_setprio(0);
    for (int i = 0; i < 4; i++) {
        int q = q0 + lg * 4 + i;
        int prow = lg * 4 + i;
        int pxor = (prow & 7) << 4;
        float rm = -1e30f;
        for (int nf = 0; nf < 4; nf++) {
            float s = sco[nf][i];
            if (diag && (kv0 + nf * 16 + lr > q)) s = -1e30f;
            sco[nf][i] = s;
            rm = fmaxf(rm, s);
        }
        rm = fmaxf(rm, __shfl_xor(rm, 1, 64));
        rm = fmaxf(rm, __shfl_xor(rm, 2, 64));
        rm = fmaxf(rm, __shfl_xor(rm, 4, 64));
        rm = fmaxf(rm, __shfl_xor(rm, 8, 64));
        float mnew = fmaxf(m_run[i], rm);
        float sum = 0.f;
        for (int nf = 0; nf < 4; nf++) {
            float pv = __expf(sco[nf][i] - mnew);
            sum += pv;
            pl[prow * 64 + ((((nf * 16 + lr) << 1) ^ pxor) >> 1)] = f2b(pv);
        }
        sum += __shfl_xor(sum, 1, 64);
        sum += __shfl_xor(sum, 2, 64);
        sum += __shfl_xor(sum, 4, 64);
        sum += __shfl_xor(sum, 8, 64);
        float cf = __expf(m_run[i] - mnew);
        l_run[i] = l_run[i] * cf + sum;
        m_run[i] = mnew;
        for (int nd = 0; nd < 4; nd++) o[nd][i] *= cf;
    }
    bf16x8 pf[2];
    for (int kk = 0; kk < 2; kk++)
        pf[kk] = *reinterpret_cast<const bf16x8*>(
            &pl[lr * 64 + (((kk * 64 + lg * 16) ^ rxor) >> 1)]);
    __builtin_amdgcn_s_setprio(1);
    for (int nd = 0; nd < 4; nd++)
        for (int kk = 0; kk < 2; kk++) {
            bf16x8 vf = *reinterpret_cast<const bf16x8*>(
                &Vl[(nd * 16 + lr) * 64 + (((kk * 64 + lg * 16) ^ rxor) >> 1)]);
            o[nd] = MFMA(pf[kk], vf, o[nd]);
        }
    __builtin_amdgcn_s_setprio(0);
}

// ---------------- flash attention (causal), work-balanced pairing ----------------
// grid (16, B*H). Block p handles q-tiles qtA=p and qtB=31-p (64 rows each);
// every wave owns 16 rows of A AND 16 rows of B. One pass over KV tiles
// 0..qtB: B always computed, A while t <= qtA -> every block = 33 tile-units.
__global__ __launch_bounds__(256) void k_attn(const unsigned short* __restrict__ Q,
                                              const unsigned short* __restrict__ Kg,
                                              const unsigned short* __restrict__ Vt,
                                              unsigned short* __restrict__ ctx) {
    int p = blockIdx.x;
    int bh = blockIdx.y;
    int b = bh >> 4, h = bh & 15;
    int tid = threadIdx.x, wid = tid >> 6, lane = tid & 63;
    int lr = lane & 15, lg = lane >> 4;
    int qtA = p, qtB = 31 - p;                 // qtB > qtA for p in 0..15
    int q0A = qtA * 64 + wid * 16;
    int q0B = qtB * 64 + wid * 16;

    __shared__ __align__(16) unsigned short Ks[2][64 * 64];   // [kv][hd], swizzled
    __shared__ __align__(16) unsigned short Vs[2][64 * 64];   // [hd][s],  swizzled
    __shared__ __align__(16) unsigned short p_lds[4][16 * 64];
    unsigned short* pl = p_lds[wid];

    const unsigned short* Qp = Q  + (size_t)b * S_ * DOUT + (size_t)h * HD_;
    const unsigned short* Kp = Kg + (size_t)b * S_ * DOUT + (size_t)h * HD_;
    const unsigned short* Vp = Vt + (size_t)(b * H_ + h) * HD_ * S_;

    bf16x8 qfA0 = *reinterpret_cast<const bf16x8*>(&Qp[(size_t)(q0A + lr) * DOUT + lg * 8]);
    bf16x8 qfA1 = *reinterpret_cast<const bf16x8*>(&Qp[(size_t)(q0A + lr) * DOUT + 32 + lg * 8]);
    bf16x8 qfB0 = *reinterpret_cast<const bf16x8*>(&Qp[(size_t)(q0B + lr) * DOUT + lg * 8]);
    bf16x8 qfB1 = *reinterpret_cast<const bf16x8*>(&Qp[(size_t)(q0B + lr) * DOUT + 32 + lg * 8]);
    asm volatile("" : "+v"(qfA0), "+v"(qfA1), "+v"(qfB0), "+v"(qfB1));

    int srow_base = (lane >> 3);
    int scolB = ((lane & 7) ^ (lane >> 3)) << 4;
    int sel = scolB >> 1;

#define STAGE_KV(buf, t)                                                           \
    {                                                                              \
        int kv0_ = (t) * 64;                                                       \
        for (int c = 0; c < 2; c++) {                                              \
            int chunk = wid * 2 + c;                                               \
            int row = chunk * 8 + srow_base;                                       \
            GLDS(Kp + (size_t)(kv0_ + row) * DOUT + sel,                           \
                 (char*)&Ks[buf][0] + chunk * 1024);                               \
            GLDS(Vp + (size_t)row * S_ + kv0_ + sel,                               \
                 (char*)&Vs[buf][0] + chunk * 1024);                               \
        }                                                                          \
    }

    STAGE_KV(0, 0)

    f32x4 oA[4] = {}, oB[4] = {};
    float mA[4], lA[4], mB[4], lB[4];
    for (int i = 0; i < 4; i++) { mA[i] = -1e30f; lA[i] = 0.f; mB[i] = -1e30f; lB[i] = 0.f; }

    int ntile = qtB + 1;
    for (int t = 0; t < ntile; t++) {
        int cur = t & 1;
        if (t + 1 < ntile) {
            STAGE_KV(cur ^ 1, t + 1)
            asm volatile("s_waitcnt vmcnt(4)" ::: "memory");
        } else {
            asm volatile("s_waitcnt vmcnt(0)" ::: "memory");
        }
        __builtin_amdgcn_s_barrier();

        int kv0 = t * 64;
        const unsigned short* Kt = Ks[cur];
        const unsigned short* Vl = Vs[cur];
        int rxor = (lr & 7) << 4;

        qk_sm_pv(Kt, Vl, pl, qfB0, qfB1, oB, mB, lB, q0B, kv0, t == qtB, lr, lg, rxor);
        if (t <= qtA)
            qk_sm_pv(Kt, Vl, pl, qfA0, qfA1, oA, mA, lA, q0A, kv0, t == qtA, lr, lg, rxor);

        __builtin_amdgcn_s_barrier();
    }

    for (int nd = 0; nd < 4; nd++)
        for (int i = 0; i < 4; i++) {
            float vB = oB[nd][i] / lB[i];
            ctx[((size_t)b * S_ + q0B + lg * 4 + i) * DOUT + h * HD_ + nd * 16 + lr] = f2b(vB);
            float vA = oA[nd][i] / lA[i];
            ctx[((size_t)b * S_ + q0A + lg * 4 + i) * DOUT + h * HD_ + nd * 16 + lr] = f2b(vA);
        }
#undef STAGE_KV
}

extern "C" void kernel_launch(void* const* d_in, const int* in_sizes, int n_in,
                              void* d_out, int out_size, void* d_ws, size_t ws_size,
                              hipStream_t stream) {
    const float* x  = (const float*)d_in[0];
    const float* Wq = (const float*)d_in[1];
    const float* Wk = (const float*)d_in[2];
    const float* Wv = (const float*)d_in[3];
    const float* Wo = (const float*)d_in[4];
    const float* bo = (const float*)d_in[5];
    float* out = (float*)d_out;
    char* ws = (char*)d_ws;
    const size_t MB = 1u << 20;

    unsigned short* xb    = (unsigned short*)(ws);
    unsigned short* Vtb   = (unsigned short*)(ws);            // reuse of xb
    unsigned short* WqkvT = (unsigned short*)(ws + 8 * MB);
    unsigned short* WoT   = (unsigned short*)(ws + 14 * MB);
    unsigned short* Qb    = (unsigned short*)(ws + 16 * MB);
    unsigned short* Kb    = (unsigned short*)(ws + 24 * MB);
    unsigned short* Vb    = (unsigned short*)(ws + 32 * MB);
    unsigned short* ctx   = Vb;                               // reuse of Vb

    (void)in_sizes; (void)n_in; (void)out_size; (void)ws_size;

    k_cvt_x<<<dim3((M_ * DIN) / 1024), 256, 0, stream>>>(x, xb);

    dim3 tb(32, 8), tg(DOUT / 32, DIN / 32);
    k_cvt_wT<<<tg, tb, 0, stream>>>(Wq, WqkvT);
    k_cvt_wT<<<tg, tb, 0, stream>>>(Wk, WqkvT + (size_t)1024 * DIN);
    k_cvt_wT<<<tg, tb, 0, stream>>>(Wv, WqkvT + (size_t)2048 * DIN);
    k_cvt_wT<<<tg, tb, 0, stream>>>(Wo, WoT);

    // fused QKV projection (Q pre-scaled by 0.125)
    k_gemm<0><<<768, 256, 0, stream>>>(xb, WqkvT, Qb, Kb, Vb, nullptr, nullptr,
                                       M_, 3072, DIN, 24);

    dim3 gt(S_ / 64, B_ * H_);
    k_trV<<<gt, 256, 0, stream>>>(Vb, Vtb);

    // causal flash attention, work-balanced q-tile pairs
    dim3 ga(16, B_ * H_);
    k_attn<<<ga, 256, 0, stream>>>(Qb, Kb, Vtb, ctx);

    k_gemm<2><<<256, 256, 0, stream>>>(ctx, WoT, nullptr, nullptr, nullptr,
                                       out, bo, M_, DOUT, DOUT, 8);
}

// Round 5
// 157.982 us; speedup vs baseline: 4.0935x; 1.0580x over previous
//
#include <hip/hip_runtime.h>

// Problem constants
#define B_    2
#define S_    2048
#define DIN   1024
#define DOUT  1024
#define H_    16
#define HD_   64
#define M_    (B_ * S_)   // 4096 rows total

typedef __bf16 bf16x8 __attribute__((ext_vector_type(8)));
typedef float  f32x4  __attribute__((ext_vector_type(4)));

__device__ __forceinline__ f32x4 MFMA(bf16x8 a, bf16x8 b, f32x4 c) {
    return __builtin_amdgcn_mfma_f32_16x16x32_bf16(a, b, c, 0, 0, 0);
}

// float -> bf16 bits, round-to-nearest-even (epilogue paths)
__device__ __forceinline__ unsigned short f2b(float f) {
    union { float f; unsigned int u; } v; v.f = f;
    unsigned int u = v.u;
    return (unsigned short)((u + 0x7fffu + ((u >> 16) & 1u)) >> 16);
}

// async global->LDS, 16B per lane; LDS dest = wave-uniform base + lane*16
#define GLDS(gp, lp) __builtin_amdgcn_global_load_lds( \
    (const __attribute__((address_space(1))) void*)(gp), \
    (__attribute__((address_space(3))) void*)(lp), 16, 0, 0)

// Q pre-scale: 1/sqrt(64) * log2(e)  (exp2-domain softmax)
#define QSCALE 0.1803368801111204f

// ---------------- convert x (f32 -> bf16), vectorized ----------------
__global__ void k_cvt_x(const float* __restrict__ x, unsigned short* __restrict__ xb) {
    int i = (blockIdx.x * blockDim.x + threadIdx.x) * 4;
    float4 v = *reinterpret_cast<const float4*>(x + i);
    ushort4 o;
    o.x = f2b(v.x); o.y = f2b(v.y); o.z = f2b(v.z); o.w = f2b(v.w);
    *reinterpret_cast<ushort4*>(xb + i) = o;
}

// ------------- convert + transpose weight (f32 KxN -> bf16 NxK) -------------
__global__ void k_cvt_wT(const float* __restrict__ w, unsigned short* __restrict__ wt) {
    __shared__ float tile[32][33];
    int n0 = blockIdx.x * 32, k0 = blockIdx.y * 32;
    int tx = threadIdx.x, ty = threadIdx.y;
    for (int i = 0; i < 4; i++)
        tile[ty + i * 8][tx] = w[(size_t)(k0 + ty + i * 8) * DOUT + n0 + tx];
    __syncthreads();
    for (int i = 0; i < 4; i++)
        wt[(size_t)(n0 + ty + i * 8) * DIN + k0 + tx] = f2b(tile[tx][ty + i * 8]);
}

// ---- transpose V per (b,h): [b*S+s][h*HD+hd] -> [(b*H+h)*HD+hd][s] ----
__global__ __launch_bounds__(256) void k_trV(const unsigned short* __restrict__ V,
                                             unsigned short* __restrict__ Vt) {
    __shared__ unsigned short tile[64][72];
    int st = blockIdx.x, bh = blockIdx.y;
    int b = bh >> 4, h = bh & 15;
    int t = threadIdx.x;
    int r = t >> 2, c = (t & 3) << 4;
    const unsigned short* src = V + (size_t)(b * S_ + st * 64 + r) * DOUT + h * HD_ + c;
    *reinterpret_cast<int4*>(&tile[r][c])     = *reinterpret_cast<const int4*>(src);
    *reinterpret_cast<int4*>(&tile[r][c + 8]) = *reinterpret_cast<const int4*>(src + 8);
    __syncthreads();
    unsigned short o[16];
    for (int j = 0; j < 16; j++) o[j] = tile[c + j][r];
    unsigned short* dst = Vt + (size_t)(bh * 64 + r) * S_ + st * 64 + c;
    *reinterpret_cast<int4*>(dst)     = *reinterpret_cast<int4*>(&o[0]);
    *reinterpret_cast<int4*>(dst + 8) = *reinterpret_cast<int4*>(&o[8]);
}

// ---------------- bf16 MFMA GEMM: C[M,N] = A[M,K] @ Bt[N,K]^T ----------------
// OUT_MODE 0: QKV fused — row-major bf16; Q pre-scaled by QSCALE.
// OUT_MODE 2: f32 out + bias
template <int OUT_MODE>
__global__ __launch_bounds__(256) void k_gemm(const unsigned short* __restrict__ A,
                                              const unsigned short* __restrict__ Bt,
                                              unsigned short* __restrict__ Cq,
                                              unsigned short* __restrict__ Ck,
                                              unsigned short* __restrict__ Cv,
                                              float* __restrict__ Cf,
                                              const float* __restrict__ bias,
                                              int M, int N, int K, int nbx) {
    __shared__ __align__(16) unsigned short As[128 * 32];
    __shared__ __align__(16) unsigned short Bs[128 * 32];

    // XCD-aware swizzle (nwg % 8 == 0)
    int nwg = gridDim.x;
    int chunk = nwg >> 3;
    int bid = blockIdx.x;
    int nid = (bid & 7) * chunk + (bid >> 3);
    int by = nid / nbx, bx = nid - by * nbx;
    int m0 = by * 128, n0 = bx * 128;

    int tid = threadIdx.x;
    int wid = tid >> 6, lane = tid & 63;
    int wm = wid >> 1, wn = wid & 1;
    int lr = lane & 15, lg = lane >> 4;

    f32x4 acc[4][4] = {};

    int ar = wid * 16 + (lane >> 2);
    int ac = (lane & 3) * 8;

    for (int k0 = 0; k0 < K; k0 += 32) {
        GLDS(A  + (size_t)(m0 + ar) * K + k0 + ac,      (char*)As + wid * 1024);
        GLDS(A  + (size_t)(m0 + 64 + ar) * K + k0 + ac, (char*)As + 4096 + wid * 1024);
        GLDS(Bt + (size_t)(n0 + ar) * K + k0 + ac,      (char*)Bs + wid * 1024);
        GLDS(Bt + (size_t)(n0 + 64 + ar) * K + k0 + ac, (char*)Bs + 4096 + wid * 1024);
        __syncthreads();

        bf16x8 af[4], bf[4];
        for (int mi = 0; mi < 4; mi++)
            af[mi] = *reinterpret_cast<const bf16x8*>(&As[(wm * 64 + mi * 16 + lr) * 32 + lg * 8]);
        for (int ni = 0; ni < 4; ni++)
            bf[ni] = *reinterpret_cast<const bf16x8*>(&Bs[(wn * 64 + ni * 16 + lr) * 32 + lg * 8]);
        for (int mi = 0; mi < 4; mi++)
            for (int ni = 0; ni < 4; ni++)
                acc[mi][ni] = MFMA(af[mi], bf[ni], acc[mi][ni]);
        __syncthreads();
    }

    for (int mi = 0; mi < 4; mi++)
        for (int ni = 0; ni < 4; ni++)
            for (int i = 0; i < 4; i++) {
                int row = m0 + wm * 64 + mi * 16 + lg * 4 + i;
                int col = n0 + wn * 64 + ni * 16 + lr;
                float v = acc[mi][ni][i];
                if (OUT_MODE == 2) {
                    Cf[(size_t)row * N + col] = v + bias[col];
                } else {
                    if (col < 1024)       Cq[(size_t)row * 1024 + col] = f2b(v * QSCALE);
                    else if (col < 2048)  Ck[(size_t)row * 1024 + (col - 1024)] = f2b(v);
                    else                  Cv[(size_t)row * 1024 + (col - 2048)] = f2b(v);
                }
            }
}

// ---- per-KV-tile (128 cols) QK^T -> online softmax (base-2) -> PV ----
// for one 16-row q-chunk. Q pre-scaled by QSCALE; only diag tiles masked.
__device__ __forceinline__ void qk_sm_pv(const unsigned short* __restrict__ Kt,
                                         const unsigned short* __restrict__ Vl,
                                         unsigned short* __restrict__ pl,
                                         bf16x8 qf0, bf16x8 qf1,
                                         f32x4 (&o)[4], float (&m_run)[4],
                                         float (&l_run)[4],
                                         int q0, int kv0, bool diag,
                                         int lr, int lg, int rxor) {
    f32x4 sco[8];
    __builtin_amdgcn_s_setprio(1);
#pragma unroll
    for (int nf = 0; nf < 8; nf++) {
        f32x4 z = {};
#pragma unroll
        for (int kk = 0; kk < 2; kk++) {
            bf16x8 kf = *reinterpret_cast<const bf16x8*>(
                &Kt[(nf * 16 + lr) * 64 + (((kk * 64 + lg * 16) ^ rxor) >> 1)]);
            z = MFMA(kk ? qf1 : qf0, kf, z);
        }
        sco[nf] = z;
    }
    __builtin_amdgcn_s_setprio(0);
#pragma unroll
    for (int i = 0; i < 4; i++) {
        int prow = lg * 4 + i;
        int pxor = (prow & 7) << 4;
        if (diag) {
            int q = q0 + prow;
#pragma unroll
            for (int nf = 0; nf < 8; nf++)
                if (kv0 + nf * 16 + lr > q) sco[nf][i] = -1e30f;
        }
        float rm = sco[0][i];
#pragma unroll
        for (int nf = 1; nf < 8; nf++) rm = fmaxf(rm, sco[nf][i]);
        rm = fmaxf(rm, __shfl_xor(rm, 1, 64));
        rm = fmaxf(rm, __shfl_xor(rm, 2, 64));
        rm = fmaxf(rm, __shfl_xor(rm, 4, 64));
        rm = fmaxf(rm, __shfl_xor(rm, 8, 64));
        float mnew = fmaxf(m_run[i], rm);
        float sum = 0.f;
#pragma unroll
        for (int nf = 0; nf < 8; nf++) {
            float pv = exp2f(sco[nf][i] - mnew);
            sum += pv;
            ((__bf16*)pl)[prow * 128 + ((((nf * 16 + lr) << 1) ^ pxor) >> 1)] = (__bf16)pv;
        }
        sum += __shfl_xor(sum, 1, 64);
        sum += __shfl_xor(sum, 2, 64);
        sum += __shfl_xor(sum, 4, 64);
        sum += __shfl_xor(sum, 8, 64);
        float cf = exp2f(m_run[i] - mnew);
        l_run[i] = l_run[i] * cf + sum;
        m_run[i] = mnew;
#pragma unroll
        for (int nd = 0; nd < 4; nd++) o[nd][i] *= cf;
    }
    bf16x8 pf[4];
#pragma unroll
    for (int kk = 0; kk < 4; kk++)
        pf[kk] = *reinterpret_cast<const bf16x8*>(
            &pl[lr * 128 + (((kk * 64 + lg * 16) ^ rxor) >> 1)]);
    __builtin_amdgcn_s_setprio(1);
#pragma unroll
    for (int nd = 0; nd < 4; nd++)
#pragma unroll
        for (int kk = 0; kk < 4; kk++) {
            bf16x8 vf = *reinterpret_cast<const bf16x8*>(
                &Vl[(nd * 16 + lr) * 128 + (((kk * 64 + lg * 16) ^ rxor) >> 1)]);
            o[nd] = MFMA(pf[kk], vf, o[nd]);
        }
    __builtin_amdgcn_s_setprio(0);
}

// ---------------- flash attention (causal), work-balanced pairing ----------------
// grid (16, B*H). Block p handles q-tiles qtA=p, qtB=31-p (64 rows each, 4 waves
// x 16 rows, each wave owns rows of BOTH tiles). One pass over KV tiles of 128.
__global__ __launch_bounds__(256, 2) void k_attn(const unsigned short* __restrict__ Q,
                                                 const unsigned short* __restrict__ Kg,
                                                 const unsigned short* __restrict__ Vt,
                                                 unsigned short* __restrict__ ctx) {
    int p = blockIdx.x;
    int bh = blockIdx.y;
    int b = bh >> 4, h = bh & 15;
    int tid = threadIdx.x, wid = tid >> 6, lane = tid & 63;
    int lr = lane & 15, lg = lane >> 4;
    int qtA = p, qtB = 31 - p;
    int q0A = qtA * 64 + wid * 16;
    int q0B = qtB * 64 + wid * 16;

    __shared__ __align__(16) unsigned short Ks[2][128 * 64];   // [kv][hd], swizzled
    __shared__ __align__(16) unsigned short Vs[2][64 * 128];   // [hd][s],  swizzled
    __shared__ __align__(16) unsigned short p_lds[4][16 * 128];
    unsigned short* pl = p_lds[wid];

    const unsigned short* Qp = Q  + (size_t)b * S_ * DOUT + (size_t)h * HD_;
    const unsigned short* Kp = Kg + (size_t)b * S_ * DOUT + (size_t)h * HD_;
    const unsigned short* Vp = Vt + (size_t)(b * H_ + h) * HD_ * S_;

    bf16x8 qfA0 = *reinterpret_cast<const bf16x8*>(&Qp[(size_t)(q0A + lr) * DOUT + lg * 8]);
    bf16x8 qfA1 = *reinterpret_cast<const bf16x8*>(&Qp[(size_t)(q0A + lr) * DOUT + 32 + lg * 8]);
    bf16x8 qfB0 = *reinterpret_cast<const bf16x8*>(&Qp[(size_t)(q0B + lr) * DOUT + lg * 8]);
    bf16x8 qfB1 = *reinterpret_cast<const bf16x8*>(&Qp[(size_t)(q0B + lr) * DOUT + 32 + lg * 8]);
    asm volatile("" : "+v"(qfA0), "+v"(qfA1), "+v"(qfB0), "+v"(qfB1));

#define STAGE_KV(buf, t)                                                           \
    {                                                                              \
        int kv0_ = (t) * 128;                                                      \
        for (int c = 0; c < 4; c++) {                                              \
            int kc = wid * 4 + c;                                                  \
            int krow = kc * 8 + (lane >> 3);                                       \
            int kcol = ((lane & 7) ^ (lane >> 3)) * 8;                             \
            GLDS(Kp + (size_t)(kv0_ + krow) * DOUT + kcol,                         \
                 (char*)&Ks[buf][0] + kc * 1024);                                  \
            int vrow = kc * 4 + (lane >> 4);                                       \
            int vcol = ((lane & 15) ^ (vrow & 7)) * 8;                             \
            GLDS(Vp + (size_t)vrow * S_ + kv0_ + vcol,                             \
                 (char*)&Vs[buf][0] + kc * 1024);                                  \
        }                                                                          \
    }

    STAGE_KV(0, 0)

    f32x4 oA[4] = {}, oB[4] = {};
    float mA[4], lA[4], mB[4], lB[4];
    for (int i = 0; i < 4; i++) { mA[i] = -1e30f; lA[i] = 0.f; mB[i] = -1e30f; lB[i] = 0.f; }

    int diagA = (qtA * 64 + 63) >> 7;   // last KV tile A needs
    int diagB = (qtB * 64 + 63) >> 7;
    int ntile = diagB + 1;
    int rxor = (lr & 7) << 4;

    for (int t = 0; t < ntile; t++) {
        int cur = t & 1;
        if (t + 1 < ntile) {
            STAGE_KV(cur ^ 1, t + 1)
            asm volatile("s_waitcnt vmcnt(8)" ::: "memory");
        } else {
            asm volatile("s_waitcnt vmcnt(0)" ::: "memory");
        }
        __builtin_amdgcn_s_barrier();

        int kv0 = t * 128;
        const unsigned short* Kt = Ks[cur];
        const unsigned short* Vl = Vs[cur];

        qk_sm_pv(Kt, Vl, pl, qfB0, qfB1, oB, mB, lB, q0B, kv0, t == diagB, lr, lg, rxor);
        if (t <= diagA)
            qk_sm_pv(Kt, Vl, pl, qfA0, qfA1, oA, mA, lA, q0A, kv0, t == diagA, lr, lg, rxor);

        __builtin_amdgcn_s_barrier();
    }

    for (int nd = 0; nd < 4; nd++)
        for (int i = 0; i < 4; i++) {
            float vB = oB[nd][i] / lB[i];
            ((__bf16*)ctx)[((size_t)b * S_ + q0B + lg * 4 + i) * DOUT + h * HD_ + nd * 16 + lr] = (__bf16)vB;
            float vA = oA[nd][i] / lA[i];
            ((__bf16*)ctx)[((size_t)b * S_ + q0A + lg * 4 + i) * DOUT + h * HD_ + nd * 16 + lr] = (__bf16)vA;
        }
#undef STAGE_KV
}

extern "C" void kernel_launch(void* const* d_in, const int* in_sizes, int n_in,
                              void* d_out, int out_size, void* d_ws, size_t ws_size,
                              hipStream_t stream) {
    const float* x  = (const float*)d_in[0];
    const float* Wq = (const float*)d_in[1];
    const float* Wk = (const float*)d_in[2];
    const float* Wv = (const float*)d_in[3];
    const float* Wo = (const float*)d_in[4];
    const float* bo = (const float*)d_in[5];
    float* out = (float*)d_out;
    char* ws = (char*)d_ws;
    const size_t MB = 1u << 20;

    unsigned short* xb    = (unsigned short*)(ws);
    unsigned short* Vtb   = (unsigned short*)(ws);            // reuse of xb
    unsigned short* WqkvT = (unsigned short*)(ws + 8 * MB);
    unsigned short* WoT   = (unsigned short*)(ws + 14 * MB);
    unsigned short* Qb    = (unsigned short*)(ws + 16 * MB);
    unsigned short* Kb    = (unsigned short*)(ws + 24 * MB);
    unsigned short* Vb    = (unsigned short*)(ws + 32 * MB);
    unsigned short* ctx   = Vb;                               // reuse of Vb

    (void)in_sizes; (void)n_in; (void)out_size; (void)ws_size;

    k_cvt_x<<<dim3((M_ * DIN) / 1024), 256, 0, stream>>>(x, xb);

    dim3 tb(32, 8), tg(DOUT / 32, DIN / 32);
    k_cvt_wT<<<tg, tb, 0, stream>>>(Wq, WqkvT);
    k_cvt_wT<<<tg, tb, 0, stream>>>(Wk, WqkvT + (size_t)1024 * DIN);
    k_cvt_wT<<<tg, tb, 0, stream>>>(Wv, WqkvT + (size_t)2048 * DIN);
    k_cvt_wT<<<tg, tb, 0, stream>>>(Wo, WoT);

    // fused QKV projection (Q pre-scaled by QSCALE)
    k_gemm<0><<<768, 256, 0, stream>>>(xb, WqkvT, Qb, Kb, Vb, nullptr, nullptr,
                                       M_, 3072, DIN, 24);

    dim3 gt(S_ / 64, B_ * H_);
    k_trV<<<gt, 256, 0, stream>>>(Vb, Vtb);

    // causal flash attention, work-balanced q-tile pairs, KVBLK=128
    dim3 ga(16, B_ * H_);
    k_attn<<<ga, 256, 0, stream>>>(Qb, Kb, Vtb, ctx);

    k_gemm<2><<<256, 256, 0, stream>>>(ctx, WoT, nullptr, nullptr, nullptr,
                                       out, bo, M_, DOUT, DOUT, 8);
}